// Round 19
// baseline (434.009 us; speedup 1.0000x reference)
//
#include <hip/hip_runtime.h>
#include <hip/hip_bf16.h>

typedef __attribute__((ext_vector_type(8))) short bf16x8;
typedef __attribute__((ext_vector_type(16))) float f32x16;
typedef __attribute__((ext_vector_type(4))) unsigned int u32x4;

#define MFMA32(a, b, c) __builtin_amdgcn_mfma_f32_32x32x16_bf16((a), (b), (c), 0, 0, 0)

static __device__ __forceinline__ unsigned int pkbf(float lo, float hi) {
  unsigned int r;
  asm("v_cvt_pk_bf16_f32 %0, %1, %2" : "=v"(r) : "v"(lo), "v"(hi));
  return r;
}

static __device__ __forceinline__ bf16x8 u4_to_bf8(u32x4 u) {
  union { u32x4 u; bf16x8 b; } cv;
  cv.u = u;
  return cv.b;
}

static __device__ __forceinline__ f32x16 z16() {
  f32x16 z;
#pragma unroll
  for (int i = 0; i < 16; ++i) z[i] = 0.0f;
  return z;
}

// Convert one 32x32 MFMA C-tile (value at [row=(r&3)+8*(r>>2)+4*hi][col=lane&31])
// into two bf16 frags with k-runs taken from the ROW dim: f0 = rows 8*hi+{0..7},
// f1 = rows 16+8*hi+{0..7}, column (lane&31) preserved.
// v_permlane32_swap_b32 (vdst.hi <-> vsrc.lo) produces BOTH needed lane-mixed
// words per pair in ONE instruction.
static __device__ __forceinline__ void tile2frag(const f32x16 t, int hi,
                                                 bf16x8* f0, bf16x8* f1) {
  unsigned int a0 = pkbf(t[0], t[1]), a1 = pkbf(t[2], t[3]);
  unsigned int b0 = pkbf(t[4], t[5]), b1 = pkbf(t[6], t[7]);
  unsigned int c0 = pkbf(t[8], t[9]), c1 = pkbf(t[10], t[11]);
  unsigned int d0 = pkbf(t[12], t[13]), d1 = pkbf(t[14], t[15]);
  asm("v_permlane32_swap_b32 %0, %1" : "+v"(a0), "+v"(b0));
  asm("v_permlane32_swap_b32 %0, %1" : "+v"(a1), "+v"(b1));
  asm("v_permlane32_swap_b32 %0, %1" : "+v"(c0), "+v"(d0));
  asm("v_permlane32_swap_b32 %0, %1" : "+v"(c1), "+v"(d1));
  u32x4 fa, fb;
  fa[0] = a0; fa[1] = a1; fa[2] = b0; fa[3] = b1;
  fb[0] = c0; fb[1] = c1; fb[2] = d0; fb[3] = d1;
  *f0 = u4_to_bf8(fa);
  *f1 = u4_to_bf8(fb);
}

// FUSED K+Q+V projection (td-sequential). Per kb-iteration: 12 MFMAs (384 cy)
// cover 6 weight loads issued one iteration ahead; X LDS reads shared 3-ways.
// K/Q tiles -> frags immediately (W-first layout); V tiles (X-first layout)
// stay in AGPRs (v[td][tq], 64 AGPR) for conversion AFTER softmax, when the
// S-tiles' AGPRs free up (64 V + 64 S = 128 AGPR peak).
static __device__ __forceinline__ void projKQV_db(
    const unsigned short* __restrict__ wpK_base,
    const unsigned short* __restrict__ wpQ_base,
    const unsigned short* __restrict__ wpV_base,
    const float* __restrict__ bgK, const float* __restrict__ bgQ,
    const float* __restrict__ bgV,
    const unsigned short* xr0, const unsigned short* xr1, int sw, int hi,
    bf16x8 kf[2][4], bf16x8 qf[2][4],
    f32x16& v00, f32x16& v01, f32x16& v10, f32x16& v11) {  // v[td][tq]
#pragma unroll
  for (int td = 0; td < 2; ++td) {
    f32x16 cK0 = z16(), cK1 = z16(), cQ0 = z16(), cQ1 = z16();
    f32x16 cV0 = z16(), cV1 = z16();
    const unsigned short* wpK = wpK_base + td * 16384;
    const unsigned short* wpQ = wpQ_base + td * 16384;
    const unsigned short* wpV = wpV_base + td * 16384;
    bf16x8 wbK[2][2], wbQ[2][2], wbV[2][2];
#pragma unroll
    for (int j = 0; j < 2; ++j) {
      wbK[0][j] = *reinterpret_cast<const bf16x8*>(wpK + j * 512);
      wbQ[0][j] = *reinterpret_cast<const bf16x8*>(wpQ + j * 512);
      wbV[0][j] = *reinterpret_cast<const bf16x8*>(wpV + j * 512);
    }
#pragma unroll
    for (int kb = 0; kb < 16; ++kb) {
      const int cur = kb & 1, nxt = cur ^ 1;
      if (kb < 15) {
#pragma unroll
        for (int j = 0; j < 2; ++j) {
          wbK[nxt][j] =
              *reinterpret_cast<const bf16x8*>(wpK + (kb * 2 + 2 + j) * 512);
          wbQ[nxt][j] =
              *reinterpret_cast<const bf16x8*>(wpQ + (kb * 2 + 2 + j) * 512);
          wbV[nxt][j] =
              *reinterpret_cast<const bf16x8*>(wpV + (kb * 2 + 2 + j) * 512);
        }
      }
#pragma unroll
      for (int j = 0; j < 2; ++j) {
        const int eo = 8 * hi + 16 * (kb * 2 + j);
        bf16x8 x0 = *reinterpret_cast<const bf16x8*>(xr0 + (eo ^ sw));
        bf16x8 x1 = *reinterpret_cast<const bf16x8*>(xr1 + (eo ^ sw));
        __builtin_amdgcn_s_setprio(1);
        cK0 = MFMA32(wbK[cur][j], x0, cK0);
        cK1 = MFMA32(wbK[cur][j], x1, cK1);
        cQ0 = MFMA32(wbQ[cur][j], x0, cQ0);
        cQ1 = MFMA32(wbQ[cur][j], x1, cQ1);
        cV0 = MFMA32(x0, wbV[cur][j], cV0);   // X-first: rows = token, cols = d
        cV1 = MFMA32(x1, wbV[cur][j], cV1);
        __builtin_amdgcn_s_setprio(0);
      }
    }
    const float* bbK = bgK + 32 * td;
    const float* bbQ = bgQ + 32 * td;
#pragma unroll
    for (int q2 = 0; q2 < 4; ++q2) {
      float4 bK = *reinterpret_cast<const float4*>(bbK + 8 * q2 + 4 * hi);
      float4 bQ = *reinterpret_cast<const float4*>(bbQ + 8 * q2 + 4 * hi);
      cK0[4 * q2 + 0] += bK.x; cK0[4 * q2 + 1] += bK.y;
      cK0[4 * q2 + 2] += bK.z; cK0[4 * q2 + 3] += bK.w;
      cK1[4 * q2 + 0] += bK.x; cK1[4 * q2 + 1] += bK.y;
      cK1[4 * q2 + 2] += bK.z; cK1[4 * q2 + 3] += bK.w;
      cQ0[4 * q2 + 0] += bQ.x; cQ0[4 * q2 + 1] += bQ.y;
      cQ0[4 * q2 + 2] += bQ.z; cQ0[4 * q2 + 3] += bQ.w;
      cQ1[4 * q2 + 0] += bQ.x; cQ1[4 * q2 + 1] += bQ.y;
      cQ1[4 * q2 + 2] += bQ.z; cQ1[4 * q2 + 3] += bQ.w;
    }
    tile2frag(cK0, hi, &kf[0][2 * td], &kf[0][2 * td + 1]);
    tile2frag(cK1, hi, &kf[1][2 * td], &kf[1][2 * td + 1]);
    tile2frag(cQ0, hi, &qf[0][2 * td], &qf[0][2 * td + 1]);
    tile2frag(cQ1, hi, &qf[1][2 * td], &qf[1][2 * td + 1]);
    float bvv = bgV[32 * td + (threadIdx.x & 31)];
#pragma unroll
    for (int r = 0; r < 16; ++r) { cV0[r] += bvv; cV1[r] += bvv; }
    if (td == 0) { v00 = cV0; v01 = cV1; } else { v10 = cV0; v11 = cV1; }
  }
}

// Scale + bias/mask + softmax for one query tile. A lane holds only HALF the keys
// (hi-interleaved rows); lane l^32 holds the complement -> combine via shfl_xor(32).
static __device__ __forceinline__ float sm_tp(f32x16& t0, f32x16& t1,
                                              const float* BmRow, int swz, int hi) {
#pragma unroll
  for (int q2 = 0; q2 < 4; ++q2) {
    float4 b0 = *reinterpret_cast<const float4*>(BmRow + ((8 * q2 + 4 * hi) ^ swz));
    float4 b1 = *reinterpret_cast<const float4*>(BmRow + ((32 + 8 * q2 + 4 * hi) ^ swz));
    t0[4 * q2 + 0] = fmaf(t0[4 * q2 + 0], 0.125f, b0.x);
    t0[4 * q2 + 1] = fmaf(t0[4 * q2 + 1], 0.125f, b0.y);
    t0[4 * q2 + 2] = fmaf(t0[4 * q2 + 2], 0.125f, b0.z);
    t0[4 * q2 + 3] = fmaf(t0[4 * q2 + 3], 0.125f, b0.w);
    t1[4 * q2 + 0] = fmaf(t1[4 * q2 + 0], 0.125f, b1.x);
    t1[4 * q2 + 1] = fmaf(t1[4 * q2 + 1], 0.125f, b1.y);
    t1[4 * q2 + 2] = fmaf(t1[4 * q2 + 2], 0.125f, b1.z);
    t1[4 * q2 + 3] = fmaf(t1[4 * q2 + 3], 0.125f, b1.w);
  }
  float mx = t0[0];
#pragma unroll
  for (int r = 1; r < 16; ++r) mx = fmaxf(mx, t0[r]);
#pragma unroll
  for (int r = 0; r < 16; ++r) mx = fmaxf(mx, t1[r]);
  mx = fmaxf(mx, __shfl_xor(mx, 32));
  float sum = 0.f;
#pragma unroll
  for (int r = 0; r < 16; ++r) { t0[r] = __expf(t0[r] - mx); sum += t0[r]; }
#pragma unroll
  for (int r = 0; r < 16; ++r) { t1[r] = __expf(t1[r] - mx); sum += t1[r]; }
  sum += __shfl_xor(sum, 32);
  return 1.0f / sum;
}

// Pack fp32 weights -> bf16 frag-order: 32 blocks of [64][512] (Wq h0-7, Wk h0-7,
// Wv h0-7, Wo w0-7); cell (td,ke,lane)*8 = W[32*td+l31][16*ke+8*hi+{0..7}].
__global__ __launch_bounds__(256) void prep_weights(
    const float* __restrict__ Wq, const float* __restrict__ Wk,
    const float* __restrict__ Wv, const float* __restrict__ Wo,
    unsigned short* __restrict__ dst) {
  int i = blockIdx.x * 256 + threadIdx.x;   // 131072 cells x 8 elems
  int blk = i >> 12;
  int c = i & 4095;
  int td = c >> 11;
  int ke = (c >> 6) & 31;
  int lane = c & 63;
  int hi = lane >> 5, l31 = lane & 31;
  int row = 32 * td + l31;
  int e = 16 * ke + 8 * hi;
  int seg = blk >> 3, sub = blk & 7;
  const float* base = (seg == 0) ? Wq : (seg == 1) ? Wk : (seg == 2) ? Wv : Wo;
  const float* src = base + (size_t)(sub * 64 + row) * 512 + e;
  float4 v0 = reinterpret_cast<const float4*>(src)[0];
  float4 v1 = reinterpret_cast<const float4*>(src)[1];
  u32x4 o;
  o[0] = pkbf(v0.x, v0.y); o[1] = pkbf(v0.z, v0.w);
  o[2] = pkbf(v1.x, v1.y); o[3] = pkbf(v1.z, v1.w);
  *reinterpret_cast<u32x4*>(dst + (size_t)blk * 32768 + c * 8) = o;
}

// One block per window (2048 blocks), 256 threads = 4 waves; wave w handles
// heads {w, w+4}. R staged in the window's own out slot. Arch <=128, AGPR
// <=128 (V-tiles+S-tiles in C; 8 acc tiles in F). Fused K+Q+V projection.
__global__ __launch_bounds__(256, 2) void swin_fused(
    const float* __restrict__ patches,
    const float* __restrict__ bq, const float* __restrict__ bk,
    const float* __restrict__ bv, const float* __restrict__ bo,
    const float* __restrict__ posb,
    const unsigned short* __restrict__ Wbf,
    float* __restrict__ out) {
  __shared__ unsigned short Xs[64 * 512];    // X bf16, swizzled
  __shared__ float Bm[64 * 64];              // bias+mask, granule-swizzled

  const int tid = threadIdx.x;
  const int bid = blockIdx.x;                // ((b*16+y)*16+x)
  const int wxi = bid & 15;
  const int wyi = (bid >> 4) & 15;
  const int w = tid >> 6;                    // wave 0..3
  const int lane = tid & 63;
  const int l31 = lane & 31;
  const int hi = lane >> 5;

  // ---- Phase A: stage X (fp32->bf16, 5-bit granule swizzle) + build Bm ----
  const float* Xg = patches + (size_t)bid * 32768;
#pragma unroll
  for (int it = 0; it < 16; ++it) {
    int p = it * 4 + w;
    int e0 = lane << 3;
    const float4* gp = reinterpret_cast<const float4*>(Xg + p * 512 + e0);
    float4 v0 = gp[0], v1 = gp[1];
    u32x4 xv;
    xv[0] = pkbf(v0.x, v0.y); xv[1] = pkbf(v0.z, v0.w);
    xv[2] = pkbf(v1.x, v1.y); xv[3] = pkbf(v1.z, v1.w);
    *reinterpret_cast<u32x4*>(Xs + p * 512 + (e0 ^ ((p & 31) << 3))) = xv;
  }
#pragma unroll
  for (int ii = 0; ii < 16; ++ii) {
    int i = ii * 256 + tid;
    int p = i >> 6, k = i & 63;
    int pr = p >> 3, pc = p & 7, kr = k >> 3, kc = k & 7;
    float b = posb[(pr - kr + 7) * 15 + (pc - kc + 7)];
    bool mk = ((wyi == 15) && ((pr < 4) != (kr < 4))) ||
              ((wxi == 15) && ((pc < 4) != (kc < 4)));
    Bm[p * 64 + (k ^ ((p & 15) << 2))] = mk ? -1e30f : b;
  }
  __syncthreads();

  // R staging area: first 64 KiB (32768 shorts) of this window's out slot.
  unsigned short* Rws = reinterpret_cast<unsigned short*>(out) + (size_t)bid * 65536;

  const int sw = l31 << 3;
  const unsigned short* xr0 = Xs + l31 * 512;
  const unsigned short* xr1 = Xs + (l31 + 32) * 512;
  const int bswz = (l31 & 15) << 2;
#pragma unroll
  for (int hh = 0; hh < 2; ++hh) {
    const int h = w + 4 * hh;
    // Phase B: fused K+Q+V projection; V C-tiles parked in AGPR (v[td][tq])
    bf16x8 kf[2][4], qf[2][4];
    f32x16 v00, v01, v10, v11;
    projKQV_db(Wbf + (size_t)(8 + h) * 32768 + lane * 8,
               Wbf + (size_t)(0 + h) * 32768 + lane * 8,
               Wbf + (size_t)(16 + h) * 32768 + lane * 8,
               bk + h * 64, bq + h * 64, bv + h * 64,
               xr0, xr1, sw, hi, kf, qf, v00, v01, v10, v11);

    // Phase C: S^T = K' Q'^T (4 parallel tiles) + softmax
    f32x16 s00 = z16(), s01 = z16(), s10 = z16(), s11 = z16();  // s[tk][tp]
    __builtin_amdgcn_s_setprio(1);
#pragma unroll
    for (int kd = 0; kd < 4; ++kd) {
      s00 = MFMA32(kf[0][kd], qf[0][kd], s00);
      s01 = MFMA32(kf[0][kd], qf[1][kd], s01);
      s10 = MFMA32(kf[1][kd], qf[0][kd], s10);
      s11 = MFMA32(kf[1][kd], qf[1][kd], s11);
    }
    __builtin_amdgcn_s_setprio(0);
    float sinv0 = sm_tp(s00, s10, Bm + l31 * 64, bswz, hi);
    float sinv1 = sm_tp(s01, s11, Bm + (l31 + 32) * 64, bswz, hi);
    bf16x8 pf[2][4];
    tile2frag(s00, hi, &pf[0][0], &pf[0][1]);
    tile2frag(s10, hi, &pf[0][2], &pf[0][3]);
    tile2frag(s01, hi, &pf[1][0], &pf[1][1]);
    tile2frag(s11, hi, &pf[1][2], &pf[1][3]);

    // V frags now that S-tiles are dead: vf[td][ks]
    bf16x8 vf[2][4];
    tile2frag(v00, hi, &vf[0][0], &vf[0][1]);   // td0, tq0
    tile2frag(v01, hi, &vf[0][2], &vf[0][3]);   // td0, tq1
    tile2frag(v10, hi, &vf[1][0], &vf[1][1]);   // td1, tq0
    tile2frag(v11, hi, &vf[1][2], &vf[1][3]);   // td1, tq1

    // Phase E: R^T = V^T @ P (4 parallel tiles), normalize, frag, store to Rws.
    // Rws layout: [tq][ke][lane]*8 holding R[p=32*tq+l31][hd=16*ke+8*hi+{0..7}];
    // this head's ke = h*4 + {0..3}.
    f32x16 r00 = z16(), r01 = z16(), r10 = z16(), r11 = z16();  // r[td][tp]
    __builtin_amdgcn_s_setprio(1);
#pragma unroll
    for (int ks = 0; ks < 4; ++ks) {
      r00 = MFMA32(vf[0][ks], pf[0][ks], r00); r01 = MFMA32(vf[0][ks], pf[1][ks], r01);
      r10 = MFMA32(vf[1][ks], pf[0][ks], r10); r11 = MFMA32(vf[1][ks], pf[1][ks], r11);
    }
    __builtin_amdgcn_s_setprio(0);
#pragma unroll
    for (int r = 0; r < 16; ++r) {
      r00[r] *= sinv0; r10[r] *= sinv0;
      r01[r] *= sinv1; r11[r] *= sinv1;
    }
    {
      bf16x8 f0, f1;
      unsigned short* rl = Rws + lane * 8;
      tile2frag(r00, hi, &f0, &f1);   // td0, tp0 -> ke = h*4 + {0,1}, tq=0
      *reinterpret_cast<bf16x8*>(rl + (h * 4 + 0) * 512) = f0;
      *reinterpret_cast<bf16x8*>(rl + (h * 4 + 1) * 512) = f1;
      tile2frag(r01, hi, &f0, &f1);   // td0, tp1 -> tq=1
      *reinterpret_cast<bf16x8*>(rl + 16384 + (h * 4 + 0) * 512) = f0;
      *reinterpret_cast<bf16x8*>(rl + 16384 + (h * 4 + 1) * 512) = f1;
      tile2frag(r10, hi, &f0, &f1);   // td1, tp0 -> ke = h*4 + {2,3}, tq=0
      *reinterpret_cast<bf16x8*>(rl + (h * 4 + 2) * 512) = f0;
      *reinterpret_cast<bf16x8*>(rl + (h * 4 + 3) * 512) = f1;
      tile2frag(r11, hi, &f0, &f1);   // td1, tp1 -> tq=1
      *reinterpret_cast<bf16x8*>(rl + 16384 + (h * 4 + 2) * 512) = f0;
      *reinterpret_cast<bf16x8*>(rl + 16384 + (h * 4 + 3) * 512) = f1;
    }
  }

  __syncthreads();  // drain R stores (vmcnt 0) + barrier: R visible block-wide

  // ---- Phase F: out = R @ Wo^T (+bo); wave w owns cols 128w..128w+127.
  // All 8 C-tiles accumulate simultaneously in AGPRs; per-kc dbuf prefetch
  // of r/wo streams.
  f32x16 acc[2][2][2];   // [pass][j][tq] — all indices compile-time
#pragma unroll
  for (int p2 = 0; p2 < 2; ++p2)
#pragma unroll
    for (int j = 0; j < 2; ++j)
#pragma unroll
      for (int tq = 0; tq < 2; ++tq)
        acc[p2][j][tq] = z16();
  {
    const unsigned short* rl = Rws + lane * 8;
    const unsigned short* wp = Wbf + (size_t)(24 + 2 * w) * 32768 + lane * 8;
    bf16x8 rb[2][2], wob[2][4];   // [buf][stream]
    rb[0][0] = *reinterpret_cast<const bf16x8*>(rl);
    rb[0][1] = *reinterpret_cast<const bf16x8*>(rl + 16384);
    wob[0][0] = *reinterpret_cast<const bf16x8*>(wp);
    wob[0][1] = *reinterpret_cast<const bf16x8*>(wp + 16384);
    wob[0][2] = *reinterpret_cast<const bf16x8*>(wp + 32768);
    wob[0][3] = *reinterpret_cast<const bf16x8*>(wp + 49152);
#pragma unroll
    for (int kc = 0; kc < 32; ++kc) {
      const int cur = kc & 1, nxt = cur ^ 1;
      if (kc < 31) {
        rb[nxt][0] = *reinterpret_cast<const bf16x8*>(rl + (kc + 1) * 512);
        rb[nxt][1] = *reinterpret_cast<const bf16x8*>(rl + 16384 + (kc + 1) * 512);
        wob[nxt][0] = *reinterpret_cast<const bf16x8*>(wp + (kc + 1) * 512);
        wob[nxt][1] = *reinterpret_cast<const bf16x8*>(wp + 16384 + (kc + 1) * 512);
        wob[nxt][2] = *reinterpret_cast<const bf16x8*>(wp + 32768 + (kc + 1) * 512);
        wob[nxt][3] = *reinterpret_cast<const bf16x8*>(wp + 49152 + (kc + 1) * 512);
      }
      __builtin_amdgcn_s_setprio(1);
      acc[0][0][0] = MFMA32(rb[cur][0], wob[cur][0], acc[0][0][0]);
      acc[0][0][1] = MFMA32(rb[cur][1], wob[cur][0], acc[0][0][1]);
      acc[0][1][0] = MFMA32(rb[cur][0], wob[cur][1], acc[0][1][0]);
      acc[0][1][1] = MFMA32(rb[cur][1], wob[cur][1], acc[0][1][1]);
      acc[1][0][0] = MFMA32(rb[cur][0], wob[cur][2], acc[1][0][0]);
      acc[1][0][1] = MFMA32(rb[cur][1], wob[cur][2], acc[1][0][1]);
      acc[1][1][0] = MFMA32(rb[cur][0], wob[cur][3], acc[1][1][0]);
      acc[1][1][1] = MFMA32(rb[cur][1], wob[cur][3], acc[1][1][1]);
      __builtin_amdgcn_s_setprio(0);
    }
  }
  __syncthreads();  // all waves done READING R; slot may now be overwritten

  float* og = out + (size_t)bid * 32768;
#pragma unroll
  for (int pass = 0; pass < 2; ++pass) {
#pragma unroll
    for (int j = 0; j < 2; ++j) {
      int col0 = 128 * w + 64 * pass + 32 * j + l31;
      float bov = bo[col0];
#pragma unroll
      for (int tq = 0; tq < 2; ++tq) {
        const f32x16& t = acc[pass][j][tq];
#pragma unroll
        for (int r = 0; r < 16; ++r) {
          int p = (r & 3) + 8 * (r >> 2) + 4 * hi + 32 * tq;
          og[p * 512 + col0] = t[r] + bov;
        }
      }
    }
  }
}

extern "C" void kernel_launch(void* const* d_in, const int* in_sizes, int n_in,
                              void* d_out, int out_size, void* d_ws, size_t ws_size,
                              hipStream_t stream) {
  const float* patches = (const float*)d_in[0];
  const float* Wq = (const float*)d_in[1];
  const float* bq = (const float*)d_in[2];
  const float* Wk = (const float*)d_in[3];
  const float* bk = (const float*)d_in[4];
  const float* Wv = (const float*)d_in[5];
  const float* bv = (const float*)d_in[6];
  const float* Wo = (const float*)d_in[7];
  const float* bo = (const float*)d_in[8];
  const float* posb = (const float*)d_in[9];
  // mask (d_in[10]) / bias_idx (d_in[11],[12]) recomputed on device.
  unsigned short* wbf = (unsigned short*)d_ws;   // 2 MiB
  hipLaunchKernelGGL(prep_weights, dim3(512), dim3(256), 0, stream, Wq, Wk, Wv, Wo, wbf);
  hipLaunchKernelGGL(swin_fused, dim3(2048), dim3(256), 0, stream,
                     patches, bq, bk, bv, bo, posb, wbf, (float*)d_out);
}

// Round 20
// 343.213 us; speedup vs baseline: 1.2645x; 1.2645x over previous
//
#include <hip/hip_runtime.h>
#include <hip/hip_bf16.h>

typedef __attribute__((ext_vector_type(8))) short bf16x8;
typedef __attribute__((ext_vector_type(16))) float f32x16;
typedef __attribute__((ext_vector_type(4))) unsigned int u32x4;

#define MFMA32(a, b, c) __builtin_amdgcn_mfma_f32_32x32x16_bf16((a), (b), (c), 0, 0, 0)

static __device__ __forceinline__ unsigned int pkbf(float lo, float hi) {
  unsigned int r;
  asm("v_cvt_pk_bf16_f32 %0, %1, %2" : "=v"(r) : "v"(lo), "v"(hi));
  return r;
}

static __device__ __forceinline__ bf16x8 u4_to_bf8(u32x4 u) {
  union { u32x4 u; bf16x8 b; } cv;
  cv.u = u;
  return cv.b;
}

static __device__ __forceinline__ f32x16 z16() {
  f32x16 z;
#pragma unroll
  for (int i = 0; i < 16; ++i) z[i] = 0.0f;
  return z;
}

// Convert one 32x32 MFMA C-tile (value at [row=(r&3)+8*(r>>2)+4*hi][col=lane&31])
// into two bf16 frags with k-runs taken from the ROW dim: f0 = rows 8*hi+{0..7},
// f1 = rows 16+8*hi+{0..7}, column (lane&31) preserved.
// v_permlane32_swap_b32 (vdst.hi <-> vsrc.lo) produces BOTH needed lane-mixed
// words per pair in ONE instruction: a' = [a.lo | b.lo] (= hi?shfl(b,32):a),
// b' = [a.hi | b.hi] (= hi?b:shfl(a,32)).
static __device__ __forceinline__ void tile2frag(const f32x16 t, int hi,
                                                 bf16x8* f0, bf16x8* f1) {
  unsigned int a0 = pkbf(t[0], t[1]), a1 = pkbf(t[2], t[3]);
  unsigned int b0 = pkbf(t[4], t[5]), b1 = pkbf(t[6], t[7]);
  unsigned int c0 = pkbf(t[8], t[9]), c1 = pkbf(t[10], t[11]);
  unsigned int d0 = pkbf(t[12], t[13]), d1 = pkbf(t[14], t[15]);
  asm("v_permlane32_swap_b32 %0, %1" : "+v"(a0), "+v"(b0));
  asm("v_permlane32_swap_b32 %0, %1" : "+v"(a1), "+v"(b1));
  asm("v_permlane32_swap_b32 %0, %1" : "+v"(c0), "+v"(d0));
  asm("v_permlane32_swap_b32 %0, %1" : "+v"(c1), "+v"(d1));
  u32x4 fa, fb;
  fa[0] = a0; fa[1] = a1; fa[2] = b0; fa[3] = b1;
  fb[0] = c0; fb[1] = c1; fb[2] = d0; fb[3] = d1;
  *f0 = u4_to_bf8(fa);
  *f1 = u4_to_bf8(fb);
}

// FUSED K+Q projection (W-first), td-sequential. Per kb-iteration: 8 MFMAs
// (256 cy) cover 4 weight loads issued one iteration ahead -> full L2 latency
// cover; X LDS reads shared by both streams. 4 C-tiles = 64 AGPR.
static __device__ __forceinline__ void projKQ_db(
    const unsigned short* __restrict__ wpK_base,
    const unsigned short* __restrict__ wpQ_base,
    const float* __restrict__ bgK, const float* __restrict__ bgQ,
    const unsigned short* xr0, const unsigned short* xr1, int sw, int hi,
    bf16x8 kf[2][4], bf16x8 qf[2][4]) {
#pragma unroll
  for (int td = 0; td < 2; ++td) {
    f32x16 cK0 = z16(), cK1 = z16(), cQ0 = z16(), cQ1 = z16();
    const unsigned short* wpK = wpK_base + td * 16384;
    const unsigned short* wpQ = wpQ_base + td * 16384;
    bf16x8 wbK[2][2], wbQ[2][2];
#pragma unroll
    for (int j = 0; j < 2; ++j) {
      wbK[0][j] = *reinterpret_cast<const bf16x8*>(wpK + j * 512);
      wbQ[0][j] = *reinterpret_cast<const bf16x8*>(wpQ + j * 512);
    }
#pragma unroll
    for (int kb = 0; kb < 16; ++kb) {
      const int cur = kb & 1, nxt = cur ^ 1;
      if (kb < 15) {
#pragma unroll
        for (int j = 0; j < 2; ++j) {
          wbK[nxt][j] =
              *reinterpret_cast<const bf16x8*>(wpK + (kb * 2 + 2 + j) * 512);
          wbQ[nxt][j] =
              *reinterpret_cast<const bf16x8*>(wpQ + (kb * 2 + 2 + j) * 512);
        }
      }
#pragma unroll
      for (int j = 0; j < 2; ++j) {
        const int eo = 8 * hi + 16 * (kb * 2 + j);
        bf16x8 x0 = *reinterpret_cast<const bf16x8*>(xr0 + (eo ^ sw));
        bf16x8 x1 = *reinterpret_cast<const bf16x8*>(xr1 + (eo ^ sw));
        __builtin_amdgcn_s_setprio(1);
        cK0 = MFMA32(wbK[cur][j], x0, cK0);
        cK1 = MFMA32(wbK[cur][j], x1, cK1);
        cQ0 = MFMA32(wbQ[cur][j], x0, cQ0);
        cQ1 = MFMA32(wbQ[cur][j], x1, cQ1);
        __builtin_amdgcn_s_setprio(0);
      }
    }
    const float* bbK = bgK + 32 * td;
    const float* bbQ = bgQ + 32 * td;
#pragma unroll
    for (int q2 = 0; q2 < 4; ++q2) {
      float4 bK = *reinterpret_cast<const float4*>(bbK + 8 * q2 + 4 * hi);
      float4 bQ = *reinterpret_cast<const float4*>(bbQ + 8 * q2 + 4 * hi);
      cK0[4 * q2 + 0] += bK.x; cK0[4 * q2 + 1] += bK.y;
      cK0[4 * q2 + 2] += bK.z; cK0[4 * q2 + 3] += bK.w;
      cK1[4 * q2 + 0] += bK.x; cK1[4 * q2 + 1] += bK.y;
      cK1[4 * q2 + 2] += bK.z; cK1[4 * q2 + 3] += bK.w;
      cQ0[4 * q2 + 0] += bQ.x; cQ0[4 * q2 + 1] += bQ.y;
      cQ0[4 * q2 + 2] += bQ.z; cQ0[4 * q2 + 3] += bQ.w;
      cQ1[4 * q2 + 0] += bQ.x; cQ1[4 * q2 + 1] += bQ.y;
      cQ1[4 * q2 + 2] += bQ.z; cQ1[4 * q2 + 3] += bQ.w;
    }
    tile2frag(cK0, hi, &kf[0][2 * td], &kf[0][2 * td + 1]);
    tile2frag(cK1, hi, &kf[1][2 * td], &kf[1][2 * td + 1]);
    tile2frag(cQ0, hi, &qf[0][2 * td], &qf[0][2 * td + 1]);
    tile2frag(cQ1, hi, &qf[1][2 * td], &qf[1][2 * td + 1]);
  }
}

// Scale + bias/mask + softmax for one query tile. A lane holds only HALF the keys
// (hi-interleaved rows); lane l^32 holds the complement -> combine via shfl_xor(32).
static __device__ __forceinline__ float sm_tp(f32x16& t0, f32x16& t1,
                                              const float* BmRow, int swz, int hi) {
#pragma unroll
  for (int q2 = 0; q2 < 4; ++q2) {
    float4 b0 = *reinterpret_cast<const float4*>(BmRow + ((8 * q2 + 4 * hi) ^ swz));
    float4 b1 = *reinterpret_cast<const float4*>(BmRow + ((32 + 8 * q2 + 4 * hi) ^ swz));
    t0[4 * q2 + 0] = fmaf(t0[4 * q2 + 0], 0.125f, b0.x);
    t0[4 * q2 + 1] = fmaf(t0[4 * q2 + 1], 0.125f, b0.y);
    t0[4 * q2 + 2] = fmaf(t0[4 * q2 + 2], 0.125f, b0.z);
    t0[4 * q2 + 3] = fmaf(t0[4 * q2 + 3], 0.125f, b0.w);
    t1[4 * q2 + 0] = fmaf(t1[4 * q2 + 0], 0.125f, b1.x);
    t1[4 * q2 + 1] = fmaf(t1[4 * q2 + 1], 0.125f, b1.y);
    t1[4 * q2 + 2] = fmaf(t1[4 * q2 + 2], 0.125f, b1.z);
    t1[4 * q2 + 3] = fmaf(t1[4 * q2 + 3], 0.125f, b1.w);
  }
  float mx = t0[0];
#pragma unroll
  for (int r = 1; r < 16; ++r) mx = fmaxf(mx, t0[r]);
#pragma unroll
  for (int r = 0; r < 16; ++r) mx = fmaxf(mx, t1[r]);
  mx = fmaxf(mx, __shfl_xor(mx, 32));
  float sum = 0.f;
#pragma unroll
  for (int r = 0; r < 16; ++r) { t0[r] = __expf(t0[r] - mx); sum += t0[r]; }
#pragma unroll
  for (int r = 0; r < 16; ++r) { t1[r] = __expf(t1[r] - mx); sum += t1[r]; }
  sum += __shfl_xor(sum, 32);
  return 1.0f / sum;
}

// Pack fp32 weights -> bf16 frag-order: 32 blocks of [64][512] (Wq h0-7, Wk h0-7,
// Wv h0-7, Wo w0-7); cell (td,ke,lane)*8 = W[32*td+l31][16*ke+8*hi+{0..7}].
__global__ __launch_bounds__(256) void prep_weights(
    const float* __restrict__ Wq, const float* __restrict__ Wk,
    const float* __restrict__ Wv, const float* __restrict__ Wo,
    unsigned short* __restrict__ dst) {
  int i = blockIdx.x * 256 + threadIdx.x;   // 131072 cells x 8 elems
  int blk = i >> 12;
  int c = i & 4095;
  int td = c >> 11;
  int ke = (c >> 6) & 31;
  int lane = c & 63;
  int hi = lane >> 5, l31 = lane & 31;
  int row = 32 * td + l31;
  int e = 16 * ke + 8 * hi;
  int seg = blk >> 3, sub = blk & 7;
  const float* base = (seg == 0) ? Wq : (seg == 1) ? Wk : (seg == 2) ? Wv : Wo;
  const float* src = base + (size_t)(sub * 64 + row) * 512 + e;
  float4 v0 = reinterpret_cast<const float4*>(src)[0];
  float4 v1 = reinterpret_cast<const float4*>(src)[1];
  u32x4 o;
  o[0] = pkbf(v0.x, v0.y); o[1] = pkbf(v0.z, v0.w);
  o[2] = pkbf(v1.x, v1.y); o[3] = pkbf(v1.z, v1.w);
  *reinterpret_cast<u32x4*>(dst + (size_t)blk * 32768 + c * 8) = o;
}

// One block per window (2048 blocks), 256 threads = 4 waves; wave w handles
// heads {w, w+4}. R staged in the window's own out slot. Arch <=128, AGPR
// <=128 (Phase F). Fused K+Q projection; permlane32_swap tile2frag.
__global__ __launch_bounds__(256, 2) void swin_fused(
    const float* __restrict__ patches,
    const float* __restrict__ bq, const float* __restrict__ bk,
    const float* __restrict__ bv, const float* __restrict__ bo,
    const float* __restrict__ posb,
    const unsigned short* __restrict__ Wbf,
    float* __restrict__ out) {
  __shared__ unsigned short Xs[64 * 512];    // X bf16, swizzled
  __shared__ float Bm[64 * 64];              // bias+mask, granule-swizzled

  const int tid = threadIdx.x;
  const int bid = blockIdx.x;                // ((b*16+y)*16+x)
  const int wxi = bid & 15;
  const int wyi = (bid >> 4) & 15;
  const int w = tid >> 6;                    // wave 0..3
  const int lane = tid & 63;
  const int l31 = lane & 31;
  const int hi = lane >> 5;

  // ---- Phase A: stage X (fp32->bf16, 5-bit granule swizzle) + build Bm ----
  const float* Xg = patches + (size_t)bid * 32768;
#pragma unroll
  for (int it = 0; it < 16; ++it) {
    int p = it * 4 + w;
    int e0 = lane << 3;
    const float4* gp = reinterpret_cast<const float4*>(Xg + p * 512 + e0);
    float4 v0 = gp[0], v1 = gp[1];
    u32x4 xv;
    xv[0] = pkbf(v0.x, v0.y); xv[1] = pkbf(v0.z, v0.w);
    xv[2] = pkbf(v1.x, v1.y); xv[3] = pkbf(v1.z, v1.w);
    *reinterpret_cast<u32x4*>(Xs + p * 512 + (e0 ^ ((p & 31) << 3))) = xv;
  }
#pragma unroll
  for (int ii = 0; ii < 16; ++ii) {
    int i = ii * 256 + tid;
    int p = i >> 6, k = i & 63;
    int pr = p >> 3, pc = p & 7, kr = k >> 3, kc = k & 7;
    float b = posb[(pr - kr + 7) * 15 + (pc - kc + 7)];
    bool mk = ((wyi == 15) && ((pr < 4) != (kr < 4))) ||
              ((wxi == 15) && ((pc < 4) != (kc < 4)));
    Bm[p * 64 + (k ^ ((p & 15) << 2))] = mk ? -1e30f : b;
  }
  __syncthreads();

  // R staging area: first 64 KiB (32768 shorts) of this window's out slot.
  unsigned short* Rws = reinterpret_cast<unsigned short*>(out) + (size_t)bid * 65536;

  const int sw = l31 << 3;
  const unsigned short* xr0 = Xs + l31 * 512;
  const unsigned short* xr1 = Xs + (l31 + 32) * 512;
  const int bswz = (l31 & 15) << 2;
#pragma unroll
  for (int hh = 0; hh < 2; ++hh) {
    const int h = w + 4 * hh;
    // Phase B: fused K+Q projection (td-seq, shared X reads, dbuf'd weights)
    bf16x8 kf[2][4], qf[2][4];
    projKQ_db(Wbf + (size_t)(8 + h) * 32768 + lane * 8,
              Wbf + (size_t)(0 + h) * 32768 + lane * 8,
              bk + h * 64, bq + h * 64, xr0, xr1, sw, hi, kf, qf);

    // Phase C: S^T = K' Q'^T (4 parallel tiles) + softmax
    f32x16 s00 = z16(), s01 = z16(), s10 = z16(), s11 = z16();  // s[tk][tp]
    __builtin_amdgcn_s_setprio(1);
#pragma unroll
    for (int kd = 0; kd < 4; ++kd) {
      s00 = MFMA32(kf[0][kd], qf[0][kd], s00);
      s01 = MFMA32(kf[0][kd], qf[1][kd], s01);
      s10 = MFMA32(kf[1][kd], qf[0][kd], s10);
      s11 = MFMA32(kf[1][kd], qf[1][kd], s11);
    }
    __builtin_amdgcn_s_setprio(0);
    float sinv0 = sm_tp(s00, s10, Bm + l31 * 64, bswz, hi);
    float sinv1 = sm_tp(s01, s11, Bm + (l31 + 32) * 64, bswz, hi);
    bf16x8 pf[2][4];
    tile2frag(s00, hi, &pf[0][0], &pf[0][1]);
    tile2frag(s10, hi, &pf[0][2], &pf[0][3]);
    tile2frag(s01, hi, &pf[1][0], &pf[1][1]);
    tile2frag(s11, hi, &pf[1][2], &pf[1][3]);

    // Phase D: V projection with batch-2 register-dbuf weight prefetch
    bf16x8 vf[2][4];   // vf[td][ks]
    {
      f32x16 v00 = z16(), v01 = z16(), v10 = z16(), v11 = z16();  // v[tq][td]
      const unsigned short* wp = Wbf + (size_t)(16 + h) * 32768 + lane * 8;
      bf16x8 wb[2][2][2];  // [buf][ke-in-batch][stream]
#pragma unroll
      for (int j = 0; j < 2; ++j) {
        wb[0][j][0] = *reinterpret_cast<const bf16x8*>(wp + j * 512);
        wb[0][j][1] = *reinterpret_cast<const bf16x8*>(wp + 16384 + j * 512);
      }
#pragma unroll
      for (int kb = 0; kb < 16; ++kb) {
        const int cur = kb & 1, nxt = cur ^ 1;
        if (kb < 15) {
#pragma unroll
          for (int j = 0; j < 2; ++j) {
            wb[nxt][j][0] =
                *reinterpret_cast<const bf16x8*>(wp + (kb * 2 + 2 + j) * 512);
            wb[nxt][j][1] = *reinterpret_cast<const bf16x8*>(
                wp + 16384 + (kb * 2 + 2 + j) * 512);
          }
        }
#pragma unroll
        for (int j = 0; j < 2; ++j) {
          const int eo = 8 * hi + 16 * (kb * 2 + j);
          bf16x8 x0 = *reinterpret_cast<const bf16x8*>(xr0 + (eo ^ sw));
          bf16x8 x1 = *reinterpret_cast<const bf16x8*>(xr1 + (eo ^ sw));
          __builtin_amdgcn_s_setprio(1);
          v00 = MFMA32(x0, wb[cur][j][0], v00);
          v01 = MFMA32(x0, wb[cur][j][1], v01);
          v10 = MFMA32(x1, wb[cur][j][0], v10);
          v11 = MFMA32(x1, wb[cur][j][1], v11);
          __builtin_amdgcn_s_setprio(0);
        }
      }
      float bv0 = bv[h * 64 + l31];
      float bv1 = bv[h * 64 + l31 + 32];
#pragma unroll
      for (int r = 0; r < 16; ++r) {
        v00[r] += bv0; v10[r] += bv0;
        v01[r] += bv1; v11[r] += bv1;
      }
      tile2frag(v00, hi, &vf[0][0], &vf[0][1]);
      tile2frag(v10, hi, &vf[0][2], &vf[0][3]);
      tile2frag(v01, hi, &vf[1][0], &vf[1][1]);
      tile2frag(v11, hi, &vf[1][2], &vf[1][3]);
    }

    // Phase E: R^T = V^T @ P (4 parallel tiles), normalize, frag, store to Rws.
    // Rws layout: [tq][ke][lane]*8 holding R[p=32*tq+l31][hd=16*ke+8*hi+{0..7}];
    // this head's ke = h*4 + {0..3}.
    f32x16 r00 = z16(), r01 = z16(), r10 = z16(), r11 = z16();  // r[td][tp]
    __builtin_amdgcn_s_setprio(1);
#pragma unroll
    for (int ks = 0; ks < 4; ++ks) {
      r00 = MFMA32(vf[0][ks], pf[0][ks], r00); r01 = MFMA32(vf[0][ks], pf[1][ks], r01);
      r10 = MFMA32(vf[1][ks], pf[0][ks], r10); r11 = MFMA32(vf[1][ks], pf[1][ks], r11);
    }
    __builtin_amdgcn_s_setprio(0);
#pragma unroll
    for (int r = 0; r < 16; ++r) {
      r00[r] *= sinv0; r10[r] *= sinv0;
      r01[r] *= sinv1; r11[r] *= sinv1;
    }
    {
      bf16x8 f0, f1;
      unsigned short* rl = Rws + lane * 8;
      tile2frag(r00, hi, &f0, &f1);   // td0, tp0 -> ke = h*4 + {0,1}, tq=0
      *reinterpret_cast<bf16x8*>(rl + (h * 4 + 0) * 512) = f0;
      *reinterpret_cast<bf16x8*>(rl + (h * 4 + 1) * 512) = f1;
      tile2frag(r01, hi, &f0, &f1);   // td0, tp1 -> tq=1
      *reinterpret_cast<bf16x8*>(rl + 16384 + (h * 4 + 0) * 512) = f0;
      *reinterpret_cast<bf16x8*>(rl + 16384 + (h * 4 + 1) * 512) = f1;
      tile2frag(r10, hi, &f0, &f1);   // td1, tp0 -> ke = h*4 + {2,3}, tq=0
      *reinterpret_cast<bf16x8*>(rl + (h * 4 + 2) * 512) = f0;
      *reinterpret_cast<bf16x8*>(rl + (h * 4 + 3) * 512) = f1;
      tile2frag(r11, hi, &f0, &f1);   // td1, tp1 -> tq=1
      *reinterpret_cast<bf16x8*>(rl + 16384 + (h * 4 + 2) * 512) = f0;
      *reinterpret_cast<bf16x8*>(rl + 16384 + (h * 4 + 3) * 512) = f1;
    }
  }

  __syncthreads();  // drain R stores (vmcnt 0) + barrier: R visible block-wide

  // ---- Phase F: out = R @ Wo^T (+bo); wave w owns cols 128w..128w+127.
  // All 8 C-tiles accumulate simultaneously in AGPRs; per-kc dbuf prefetch
  // of r/wo streams.
  f32x16 acc[2][2][2];   // [pass][j][tq] — all indices compile-time
#pragma unroll
  for (int p2 = 0; p2 < 2; ++p2)
#pragma unroll
    for (int j = 0; j < 2; ++j)
#pragma unroll
      for (int tq = 0; tq < 2; ++tq)
        acc[p2][j][tq] = z16();
  {
    const unsigned short* rl = Rws + lane * 8;
    const unsigned short* wp = Wbf + (size_t)(24 + 2 * w) * 32768 + lane * 8;
    bf16x8 rb[2][2], wob[2][4];   // [buf][stream]
    rb[0][0] = *reinterpret_cast<const bf16x8*>(rl);
    rb[0][1] = *reinterpret_cast<const bf16x8*>(rl + 16384);
    wob[0][0] = *reinterpret_cast<const bf16x8*>(wp);
    wob[0][1] = *reinterpret_cast<const bf16x8*>(wp + 16384);
    wob[0][2] = *reinterpret_cast<const bf16x8*>(wp + 32768);
    wob[0][3] = *reinterpret_cast<const bf16x8*>(wp + 49152);
#pragma unroll
    for (int kc = 0; kc < 32; ++kc) {
      const int cur = kc & 1, nxt = cur ^ 1;
      if (kc < 31) {
        rb[nxt][0] = *reinterpret_cast<const bf16x8*>(rl + (kc + 1) * 512);
        rb[nxt][1] = *reinterpret_cast<const bf16x8*>(rl + 16384 + (kc + 1) * 512);
        wob[nxt][0] = *reinterpret_cast<const bf16x8*>(wp + (kc + 1) * 512);
        wob[nxt][1] = *reinterpret_cast<const bf16x8*>(wp + 16384 + (kc + 1) * 512);
        wob[nxt][2] = *reinterpret_cast<const bf16x8*>(wp + 32768 + (kc + 1) * 512);
        wob[nxt][3] = *reinterpret_cast<const bf16x8*>(wp + 49152 + (kc + 1) * 512);
      }
      __builtin_amdgcn_s_setprio(1);
      acc[0][0][0] = MFMA32(rb[cur][0], wob[cur][0], acc[0][0][0]);
      acc[0][0][1] = MFMA32(rb[cur][1], wob[cur][0], acc[0][0][1]);
      acc[0][1][0] = MFMA32(rb[cur][0], wob[cur][1], acc[0][1][0]);
      acc[0][1][1] = MFMA32(rb[cur][1], wob[cur][1], acc[0][1][1]);
      acc[1][0][0] = MFMA32(rb[cur][0], wob[cur][2], acc[1][0][0]);
      acc[1][0][1] = MFMA32(rb[cur][1], wob[cur][2], acc[1][0][1]);
      acc[1][1][0] = MFMA32(rb[cur][0], wob[cur][3], acc[1][1][0]);
      acc[1][1][1] = MFMA32(rb[cur][1], wob[cur][3], acc[1][1][1]);
      __builtin_amdgcn_s_setprio(0);
    }
  }
  __syncthreads();  // all waves done READING R; slot may now be overwritten

  float* og = out + (size_t)bid * 32768;
#pragma unroll
  for (int pass = 0; pass < 2; ++pass) {
#pragma unroll
    for (int j = 0; j < 2; ++j) {
      int col0 = 128 * w + 64 * pass + 32 * j + l31;
      float bov = bo[col0];
#pragma unroll
      for (int tq = 0; tq < 2; ++tq) {
        const f32x16& t = acc[pass][j][tq];
#pragma unroll
        for (int r = 0; r < 16; ++r) {
          int p = (r & 3) + 8 * (r >> 2) + 4 * hi + 32 * tq;
          og[p * 512 + col0] = t[r] + bov;
        }
      }
    }
  }
}

extern "C" void kernel_launch(void* const* d_in, const int* in_sizes, int n_in,
                              void* d_out, int out_size, void* d_ws, size_t ws_size,
                              hipStream_t stream) {
  const float* patches = (const float*)d_in[0];
  const float* Wq = (const float*)d_in[1];
  const float* bq = (const float*)d_in[2];
  const float* Wk = (const float*)d_in[3];
  const float* bk = (const float*)d_in[4];
  const float* Wv = (const float*)d_in[5];
  const float* bv = (const float*)d_in[6];
  const float* Wo = (const float*)d_in[7];
  const float* bo = (const float*)d_in[8];
  const float* posb = (const float*)d_in[9];
  // mask (d_in[10]) / bias_idx (d_in[11],[12]) recomputed on device.
  unsigned short* wbf = (unsigned short*)d_ws;   // 2 MiB
  hipLaunchKernelGGL(prep_weights, dim3(512), dim3(256), 0, stream, Wq, Wk, Wv, Wo, wbf);
  hipLaunchKernelGGL(swin_fused, dim3(2048), dim3(256), 0, stream,
                     patches, bq, bk, bv, bo, posb, wbf, (float*)d_out);
}